// Round 20
// baseline (123.384 us; speedup 1.0000x reference)
//
#include <hip/hip_runtime.h>

using half8  = __attribute__((ext_vector_type(8))) _Float16;
using half4  = __attribute__((ext_vector_type(4))) _Float16;
using half2v = __attribute__((ext_vector_type(2))) _Float16;
using fp16x2 = __attribute__((ext_vector_type(2))) __fp16;
using f32x4  = __attribute__((ext_vector_type(4))) float;

#define BB 2
#define SS 2048
#define DD 1024
#define HH 16
#define KVH 4
#define HDIM 64
#define NQK 1280    // Q(1024) | K(256) columns of QK projection
#define LOG2E 1.4426950408889634f

// async global->LDS, 16B per lane, linear LDS dest (wave-uniform base + lane*16)
#define GLDS(g, l) __builtin_amdgcn_global_load_lds( \
    (const __attribute__((address_space(1))) void*)(g), \
    (__attribute__((address_space(3))) void*)(l), 16, 0, 0)

__device__ __forceinline__ f32x4 mfma16(half4 a, half4 b, f32x4 c) {
    return __builtin_amdgcn_mfma_f32_16x16x16f16(a, b, c, 0, 0, 0);
}

__device__ __forceinline__ float fexp2(float x) {
#if __has_builtin(__builtin_amdgcn_exp2f)
    return __builtin_amdgcn_exp2f(x);
#else
    return exp2f(x);
#endif
}

__device__ __forceinline__ half2v cvt_pk_f16(float a, float b) {
    fp16x2 r = __builtin_amdgcn_cvt_pkrtz(a, b);
    return __builtin_bit_cast(half2v, r);
}

// Attn K/V LDS tile [64 rows][64 halves], row stride 128B, XOR-swizzled 16B
// slots: slot' = slot ^ (row & 7). Applied on BOTH ds_write and all reads.
__device__ __forceinline__ int kv_off(int row, int hcol) {
    return row * 64 + ((((hcol >> 3) ^ row) & 7) << 3) + (hcol & 7);
}

// GEMM LDS tile [rows][32 halves], row stride 64B, XOR-swizzled 16B slots:
// slot' = slot ^ (row & 3). Reader-side helper (writer swizzles GLDS source).
__device__ __forceinline__ int gm_off(int row, int slot) {
    return row * 32 + (((slot ^ row) & 3) << 3);
}

// T5 bucket via integer thresholds (matches numpy fp32 logf semantics at all
// integer rel positions; verified boundary cases 12/16/23/32/46/64/91).
__device__ __forceinline__ int rel_large(int rel) { // rel >= 8
    int n;
    if (rel < 12) n = 0; else if (rel < 16) n = 1; else if (rel < 23) n = 2;
    else if (rel < 32) n = 3; else if (rel < 46) n = 4; else if (rel < 64) n = 5;
    else if (rel < 91) n = 6; else if (rel < 128) n = 7; else n = 8;
    int large = 8 + n;
    return large > 15 ? 15 : large;
}

// ---------------------------------------------------------------------------
// Fused prep: blocks 0..2559 -> weights; 2560..6655 -> cast x; 6656..6911 ->
// bias table. Q-rows of Wqk and the bias table are PRE-SCALED by log2e so the
// attention softmax runs in exp2 domain.
// rows 1280..1535 use RAW pooled Wv (value_scale unused: reference bug).
__global__ void prep_all(const float* __restrict__ x,
                         const float* __restrict__ Wq, const float* __restrict__ Wk,
                         const float* __restrict__ Wv, const float* __restrict__ Wo,
                         const float* __restrict__ ksc, const float* __restrict__ bias_emb,
                         _Float16* __restrict__ Wqk, _Float16* __restrict__ Wvb,
                         _Float16* __restrict__ Wob, float* __restrict__ tab,
                         _Float16* __restrict__ Xh)
{
    int bid = blockIdx.x;
    if (bid < 2560) {
        int row = bid;
        int c = threadIdx.x * 4;
        if (row < NQK) {
            if (row < 1024) {
                #pragma unroll
                for (int j = 0; j < 4; ++j)
                    Wqk[(size_t)row * DD + c + j] = (_Float16)(Wq[(size_t)row * DD + c + j] * LOG2E);
            } else {
                int kh = row - 1024;                  // 0..255
                int kvi = kh >> 6, hd = kh & 63;
                #pragma unroll
                for (int j = 0; j < 4; ++j) {
                    float s = 0.f;
                    #pragma unroll
                    for (int g = 0; g < 4; ++g)
                        s += Wk[(size_t)((kvi * 4 + g) * 64 + hd) * DD + c + j] * ksc[kvi * 4 + g];
                    Wqk[(size_t)row * DD + c + j] = (_Float16)s;
                }
            }
        } else if (row < 1536) {
            int vh = row - 1280;
            int kvi = vh >> 6, hd = vh & 63;
            #pragma unroll
            for (int j = 0; j < 4; ++j) {
                float s = 0.f;
                #pragma unroll
                for (int g = 0; g < 4; ++g)
                    s += Wv[(size_t)((kvi * 4 + g) * 64 + hd) * DD + c + j];
                Wvb[(size_t)vh * DD + c + j] = (_Float16)s;
            }
        } else {
            int r = row - 1536;
            #pragma unroll
            for (int j = 0; j < 4; ++j)
                Wob[(size_t)r * DD + c + j] = (_Float16)Wo[(size_t)r * DD + c + j];
        }
    } else if (bid < 6656) {
        int idx = ((bid - 2560) * 256 + threadIdx.x) * 4;
        float4 v = *(const float4*)(x + idx);
        half4 o = { (_Float16)v.x, (_Float16)v.y, (_Float16)v.z, (_Float16)v.w };
        *(half4*)(Xh + idx) = o;
    } else {
        int idx = (bid - 6656) * 256 + threadIdx.x;
        if (idx < HH * 4095) {
            int h = idx / 4095;
            int dpos = idx % 4095;
            int d = dpos - 2047;
            int rel = d < 0 ? -d : d;
            int bucket = (rel < 8) ? rel : rel_large(rel);
            if (d > 0) bucket += 16;
            tab[(size_t)h * 4095 + dpos] = bias_emb[bucket * HH + h] * LOG2E;
        }
    }
}

// ---------------------------------------------------------------------------
// C = A[M,K] @ B[N,K]^T, fp16 in, fp32 accum. 64x128 tile (M-tile 64 for
// exact CU balance: gemm<3> 768 blk = 3/CU, gemm<0> 512 blk = 2/CU), BK=32,
// 4 waves (2Mx2N, each 32x64 = 2x4 frags), 2-phase double-buffered
// global_load_lds staging (pre-swizzled source col; reads via gm_off).
// OUTK 0: C0 fp32 row-major (ldc stride).
// OUTK 3: fused projection output: cols < 1280 -> C0 fp16 row-major (ldc);
//         cols >= 1280 -> C1 fp16 TRANSPOSED (C1[(col-1280)*M + row]).
template<int OUTK>
__global__ __launch_bounds__(256) void gemm_bt(const _Float16* __restrict__ A,
                                               const _Float16* __restrict__ B,
                                               void* __restrict__ C0,
                                               _Float16* __restrict__ C1,
                                               int M, int K, int ldc)
{
    __shared__ __align__(16) _Float16 As[2][64 * 32];
    __shared__ __align__(16) _Float16 Bs[2][128 * 32];

    // XCD-bijective remap of linear block id (grid size % 8 == 0)
    int nwg = gridDim.x * gridDim.y;
    int lid = blockIdx.y * gridDim.x + blockIdx.x;
    int sid = (lid & 7) * (nwg >> 3) + (lid >> 3);
    int m0 = (sid / gridDim.x) * 64, n0 = (sid % gridDim.x) * 128;

    int t = threadIdx.x;
    int wv = t >> 6, lane = t & 63;
    int wm = wv >> 1, wn = wv & 1;
    int lr = lane & 15, lg = lane >> 4;
    int srow = lane >> 2;            // 0..15 within chunk (row = chunk*16+srow)
    // GLDS pre-swizzled source column (lane's linear slot holds logical slot^row)
    int scol = (((lane & 3) ^ (srow & 3)) << 3);
    f32x4 acc[2][4] = {};

#define GSTAGE(BUF, K0)                                                       \
    {                                                                         \
        /* A: 4 chunks of 16 rows; wave wv stages chunk wv */                 \
        GLDS(A + (size_t)(m0 + wv * 16 + srow) * K + (K0) + scol,             \
             &As[BUF][wv * 512 + lane * 8]);                                  \
        _Pragma("unroll")                                                     \
        for (int i_ = 0; i_ < 2; ++i_) {                                      \
            int chunk_ = wv * 2 + i_;                                         \
            GLDS(B + (size_t)(n0 + chunk_ * 16 + srow) * K + (K0) + scol,     \
                 &Bs[BUF][chunk_ * 512 + lane * 8]);                          \
        }                                                                     \
    }

    GSTAGE(0, 0);
    __syncthreads();          // drains vmcnt -> buf0 ready
    int cur = 0;

    for (int k0 = 0; k0 < K; k0 += 32) {
        if (k0 + 32 < K) GSTAGE(cur ^ 1, k0 + 32);   // async prefetch
        half8 af[2], bfr[4];
        #pragma unroll
        for (int mi = 0; mi < 2; ++mi)
            af[mi] = *(const half8*)(&As[cur][gm_off(wm * 32 + mi * 16 + lr, lg)]);
        #pragma unroll
        for (int ni = 0; ni < 4; ++ni)
            bfr[ni] = *(const half8*)(&Bs[cur][gm_off(wn * 64 + ni * 16 + lr, lg)]);
        __builtin_amdgcn_s_setprio(1);
        #pragma unroll
        for (int mi = 0; mi < 2; ++mi)
            #pragma unroll
            for (int ni = 0; ni < 4; ++ni)
                acc[mi][ni] = __builtin_amdgcn_mfma_f32_16x16x32_f16(af[mi], bfr[ni], acc[mi][ni], 0, 0, 0);
        __builtin_amdgcn_s_setprio(0);
        __syncthreads();      // drains prefetch vmcnt; readers of cur done
        cur ^= 1;
    }
#undef GSTAGE

    #pragma unroll
    for (int mi = 0; mi < 2; ++mi) {
        #pragma unroll
        for (int ni = 0; ni < 4; ++ni) {
            int rowb = m0 + wm * 32 + mi * 16 + 4 * lg;
            int col  = n0 + wn * 64 + ni * 16 + lr;
            if constexpr (OUTK == 0) {
                #pragma unroll
                for (int r = 0; r < 4; ++r)
                    ((float*)C0)[(size_t)(rowb + r) * ldc + col] = acc[mi][ni][r];
            } else {
                if (n0 < 1280) {
                    #pragma unroll
                    for (int r = 0; r < 4; ++r)
                        ((_Float16*)C0)[(size_t)(rowb + r) * ldc + col] = (_Float16)acc[mi][ni][r];
                } else {
                    half4 o = { (_Float16)acc[mi][ni][0], (_Float16)acc[mi][ni][1],
                                (_Float16)acc[mi][ni][2], (_Float16)acc[mi][ni][3] };
                    *(half4*)(C1 + (size_t)(col - 1280) * M + rowb) = o;
                }
            }
        }
    }
}

// ---------------------------------------------------------------------------
// Flash attention, swapped-operand QK^T, fp16. 4 waves x 2 q-groups per wave
// (128 q-rows/block, grid 512). Wave w computes q-rows {w*16+lr} (group A)
// and {64+w*16+lr} (group B); every K/V LDS fragment read is SHARED between
// the two groups (one bk/vf read feeds 2 MFMAs) — halves LDS read traffic
// vs the 8-wave version (the ~75%-busy pipe). Staging per q-row unchanged.
// Double-buffered async staging, exp2-domain softmax, XOR-swizzled K/V LDS.
// NOTE (R12-R17 post-mortems): no min-waves bound (spills); wave/block
// key-splits regress; K direct-from-L2 regresses (strided 16B/lane reads).
__global__ __launch_bounds__(256) void attn(const _Float16* __restrict__ Y,
                                            const _Float16* __restrict__ Vt,
                                            const float* __restrict__ tab,
                                            _Float16* __restrict__ O)
{
    // bijective XCD swizzle: 512 = 8 * 64; blocks sharing a (b,kv) K/V slab
    // (64 consecutive logical ids) land on one XCD's L2.
    int blk = (blockIdx.x & 7) * 64 + (blockIdx.x >> 3);
    int qb = blk & 15, h = (blk >> 4) & 15, b = blk >> 8;
    int kv = h >> 2;
    int q0 = qb * 128;
    int t = threadIdx.x, w = t >> 6, lane = t & 63, lr = lane & 15, lg = lane >> 4;

    __shared__ __align__(16) _Float16 Ks[2][64 * 64];
    __shared__ __align__(16) _Float16 Vst[2][64 * 64];
    __shared__ float bias_s[2][192];

    // Q fragments for both groups
    const size_t yoffA = (size_t)(b * SS + q0 + w * 16 + lr) * NQK + h * 64;
    const size_t yoffB = yoffA + (size_t)64 * NQK;
    half8 aq0a = *(const half8*)(Y + yoffA + lg * 8);
    half8 aq1a = *(const half8*)(Y + yoffA + 32 + lg * 8);
    half8 aq0b = *(const half8*)(Y + yoffB + lg * 8);
    half8 aq1b = *(const half8*)(Y + yoffB + 32 + lg * 8);

    // far-tile uniform bias values (bucket saturated at |d|>=128), log2-scaled
    const float bias_neg = tab[(size_t)h * 4095 + 0];      // key << q
    const float bias_pos = tab[(size_t)h * 4095 + 4094];   // key >> q

    f32x4 acc_a[4] = {}, acc_b[4] = {};
    float ma = -1e30f, la = 0.f, mb = -1e30f, lb = 0.f;
    const int bbA = 127 - w * 16 - lr + 4 * lg;   // group A bias base (+dt*16+r)
    const int bbB = bbA - 64;                     // group B

    // staging registers: 256 threads cover 64 rows x 64 halves, 16 halves each
    uint4 kreg0, kreg1, vreg0, vreg1;
    float breg = 0.f;
    const int srow = t >> 2, scb = (t & 3) << 4;   // row 0..63, col base 0/16/32/48

#define FAR(K0) (((K0) >= q0 + 256) || ((K0) <= q0 - 192))

#define ATTN_LOAD(KEY0)                                                          \
    {                                                                            \
        int k0_ = (KEY0);                                                        \
        const _Float16* kp_ = Y + (size_t)(b * SS + k0_ + srow) * NQK + 1024 + kv * 64 + scb; \
        kreg0 = *(const uint4*)(kp_);                                            \
        kreg1 = *(const uint4*)(kp_ + 8);                                        \
        const _Float16* vp_ = Vt + (size_t)(kv * 64 + srow) * 4096 + b * SS + k0_ + scb; \
        vreg0 = *(const uint4*)(vp_);                                            \
        vreg1 = *(const uint4*)(vp_ + 8);                                        \
        if (!FAR(k0_) && t < 192) {                                              \
            int ti = k0_ - q0 + t + 1920;                                        \
            ti = ti < 0 ? 0 : (ti > 4094 ? 4094 : ti);                           \
            breg = tab[(size_t)h * 4095 + ti];                                   \
        }                                                                        \
    }

#define ATTN_WRITE(BUF, KEY0)                                                    \
    {                                                                            \
        int bf_ = (BUF);                                                         \
        *(uint4*)(&Ks[bf_][kv_off(srow, scb)]) = kreg0;                          \
        *(uint4*)(&Ks[bf_][kv_off(srow, scb + 8)]) = kreg1;                      \
        *(uint4*)(&Vst[bf_][kv_off(srow, scb)]) = vreg0;                         \
        *(uint4*)(&Vst[bf_][kv_off(srow, scb + 8)]) = vreg1;                     \
        if (!FAR(KEY0) && t < 192) bias_s[bf_][t] = breg;                        \
    }

    ATTN_LOAD(0);
    ATTN_WRITE(0, 0);
    __syncthreads();
    int cur = 0;

    for (int key0 = 0; key0 < SS; key0 += 64) {
        if (key0 + 64 < SS) ATTN_LOAD(key0 + 64);   // async: regs used only in WRITE

        const _Float16* ks = Ks[cur];
        const _Float16* vs = Vst[cur];
        bool far = FAR(key0);

        // swapped QK^T for BOTH groups, sharing each K fragment read
        f32x4 z = {0.f, 0.f, 0.f, 0.f};
        f32x4 sa[4], sb[4];
        __builtin_amdgcn_s_setprio(1);
        #pragma unroll
        for (int dt = 0; dt < 4; ++dt) {
            half8 bk0 = *(const half8*)(&ks[kv_off(dt * 16 + lr, lg * 8)]);
            half8 bk1 = *(const half8*)(&ks[kv_off(dt * 16 + lr, 32 + lg * 8)]);
            sa[dt] = __builtin_amdgcn_mfma_f32_16x16x32_f16(bk0, aq0a, z, 0, 0, 0);
            sa[dt] = __builtin_amdgcn_mfma_f32_16x16x32_f16(bk1, aq1a, sa[dt], 0, 0, 0);
            sb[dt] = __builtin_amdgcn_mfma_f32_16x16x32_f16(bk0, aq0b, z, 0, 0, 0);
            sb[dt] = __builtin_amdgcn_mfma_f32_16x16x32_f16(bk1, aq1b, sb[dt], 0, 0, 0);
        }
        __builtin_amdgcn_s_setprio(0);

        float ca, cb;
        if (!far) {
            #pragma unroll
            for (int dt = 0; dt < 4; ++dt)
                #pragma unroll
                for (int r = 0; r < 4; ++r) {
                    sa[dt][r] += bias_s[cur][bbA + dt * 16 + r];
                    sb[dt][r] += bias_s[cur][bbB + dt * 16 + r];
                }
            ca = cb = 0.f;
        } else {
            ca = cb = (key0 > q0) ? bias_pos : bias_neg;
        }

        // per-lane online softmax (group A)
        {
            float pmax = sa[0][0];
            #pragma unroll
            for (int dt = 0; dt < 4; ++dt)
                #pragma unroll
                for (int r = 0; r < 4; ++r) pmax = fmaxf(pmax, sa[dt][r]);
            pmax = fmaxf(pmax, __shfl_xor(pmax, 16, 64));
            pmax = fmaxf(pmax, __shfl_xor(pmax, 32, 64));
            pmax += ca;
            if (__any(pmax > ma + 8.f)) {
                float mn = fmaxf(ma, pmax);
                float scale = fexp2(ma - mn);
                la *= scale;
                #pragma unroll
                for (int odt = 0; odt < 4; ++odt)
                    #pragma unroll
                    for (int r = 0; r < 4; ++r) acc_a[odt][r] *= scale;
                ma = mn;
            }
            float moff = ma - ca;
            float rs = 0.f;
            #pragma unroll
            for (int dt = 0; dt < 4; ++dt)
                #pragma unroll
                for (int r = 0; r < 4; ++r) {
                    float p = fexp2(sa[dt][r] - moff);
                    sa[dt][r] = p;
                    rs += p;
                }
            rs += __shfl_xor(rs, 16, 64);
            rs += __shfl_xor(rs, 32, 64);
            la += rs;
        }
        // per-lane online softmax (group B)
        {
            float pmax = sb[0][0];
            #pragma unroll
            for (int dt = 0; dt < 4; ++dt)
                #pragma unroll
                for (int r = 0; r < 4; ++r) pmax = fmaxf(pmax, sb[dt][r]);
            pmax = fmaxf(pmax, __shfl_xor(pmax, 16, 64));
            pmax = fmaxf(pmax, __shfl_xor(pmax, 32, 64));
            pmax += cb;
            if (__any(pmax > mb + 8.f)) {
                float mn = fmaxf(mb, pmax);
                float scale = fexp2(mb - mn);
                lb *= scale;
                #pragma unroll
                for (int odt = 0; odt < 4; ++odt)
                    #pragma unroll
                    for (int r = 0; r < 4; ++r) acc_b[odt][r] *= scale;
                mb = mn;
            }
            float moff = mb - cb;
            float rs = 0.f;
            #pragma unroll
            for (int dt = 0; dt < 4; ++dt)
                #pragma unroll
                for (int r = 0; r < 4; ++r) {
                    float p = fexp2(sb[dt][r] - moff);
                    sb[dt][r] = p;
                    rs += p;
                }
            rs += __shfl_xor(rs, 16, 64);
            rs += __shfl_xor(rs, 32, 64);
            lb += rs;
        }

        // pack P to fp16 B-fragments (k=4*lg+e matches 16x16x16 B layout)
        half4 pfa[4], pfb[4];
        #pragma unroll
        for (int dt = 0; dt < 4; ++dt) {
            half2v a01 = cvt_pk_f16(sa[dt][0], sa[dt][1]);
            half2v a23 = cvt_pk_f16(sa[dt][2], sa[dt][3]);
            pfa[dt] = { a01[0], a01[1], a23[0], a23[1] };
            half2v b01 = cvt_pk_f16(sb[dt][0], sb[dt][1]);
            half2v b23 = cvt_pk_f16(sb[dt][2], sb[dt][3]);
            pfb[dt] = { b01[0], b01[1], b23[0], b23[1] };
        }

        // PV for BOTH groups, sharing each V fragment read
        __builtin_amdgcn_s_setprio(1);
        #pragma unroll
        for (int odt = 0; odt < 4; ++odt)
            #pragma unroll
            for (int dt = 0; dt < 4; ++dt) {
                half4 vf = *(const half4*)(&vs[kv_off(odt * 16 + lr, dt * 16 + 4 * lg)]);
                acc_a[odt] = mfma16(vf, pfa[dt], acc_a[odt]);
                acc_b[odt] = mfma16(vf, pfb[dt], acc_b[odt]);
            }
        __builtin_amdgcn_s_setprio(0);

        if (key0 + 64 < SS) {
            ATTN_WRITE(cur ^ 1, key0 + 64);   // waits vmcnt for regs, fills other buf
            __syncthreads();                  // single barrier per tile
            cur ^= 1;
        }
    }

    // epilogue: both q-groups, d = odt*16 + 4*lg + r (half4 stores)
    float inva = 1.f / la, invb = 1.f / lb;
    _Float16* orowA = O + (size_t)(b * SS + q0 + w * 16 + lr) * 1024 + h * 64;
    _Float16* orowB = orowA + (size_t)64 * 1024;
    #pragma unroll
    for (int odt = 0; odt < 4; ++odt) {
        half4 oa = { (_Float16)(acc_a[odt][0] * inva), (_Float16)(acc_a[odt][1] * inva),
                     (_Float16)(acc_a[odt][2] * inva), (_Float16)(acc_a[odt][3] * inva) };
        *(half4*)(orowA + odt * 16 + 4 * lg) = oa;
        half4 ob = { (_Float16)(acc_b[odt][0] * invb), (_Float16)(acc_b[odt][1] * invb),
                     (_Float16)(acc_b[odt][2] * invb), (_Float16)(acc_b[odt][3] * invb) };
        *(half4*)(orowB + odt * 16 + 4 * lg) = ob;
    }
#undef ATTN_LOAD
#undef ATTN_WRITE
#undef FAR
}

// ---------------------------------------------------------------------------
extern "C" void kernel_launch(void* const* d_in, const int* in_sizes, int n_in,
                              void* d_out, int out_size, void* d_ws, size_t ws_size,
                              hipStream_t stream)
{
    const float* x   = (const float*)d_in[0];
    const float* Wq  = (const float*)d_in[1];
    const float* Wk  = (const float*)d_in[2];
    const float* Wv  = (const float*)d_in[3];
    const float* Wo  = (const float*)d_in[4];
    const float* ksc = (const float*)d_in[5];
    // d_in[6] (value_scale) intentionally unused — reference pools raw Wv
    const float* bias_emb = (const float*)d_in[7];
    float* out = (float*)d_out;

    char* ws = (char*)d_ws;
    // workspace layout (bytes); Wqk and Wvb MUST be adjacent (fused GEMM B)
    _Float16* Wqk = (_Float16*)(ws);                  // 1280*1024*2 =  2,621,440
    _Float16* Wvb = (_Float16*)(ws + 2621440);        //  256*1024*2 =    524,288
    _Float16* Wob = (_Float16*)(ws + 3145728);        // 1024*1024*2 =  2,097,152
    float*    tab = (float*)(ws + 5242880);           // 16*4095*4   =    262,080 (+pad)
    _Float16* Xh  = (_Float16*)(ws + 5505024);        // 4096*1024*2 =  8,388,608
    _Float16* Y   = (_Float16*)(ws + 13893632);       // 4096*1280*2 = 10,485,760
    _Float16* Vt  = (_Float16*)(ws + 24379392);       //  256*4096*2 =  2,097,152
    _Float16* Ob  = (_Float16*)(ws + 26476544);       // 4096*1024*2 =  8,388,608
    // total: 34,865,152 bytes

    // fused prep: weights (log2e-folded Q), x cast, bias table (log2e-scaled)
    prep_all<<<6912, 256, 0, stream>>>(x, Wq, Wk, Wv, Wo, ksc, bias_emb,
                                       Wqk, Wvb, Wob, tab, Xh);

    // fused Q|K|V projection: [4096,1024] @ [1536,1024]^T, 64x128 tiles
    // cols 0..1279 -> Y row-major; cols 1280..1535 -> Vt transposed
    gemm_bt<3><<<dim3(12, 64), 256, 0, stream>>>(Xh, Wqk, Y, Vt, 4096, 1024, NQK);

    // flash attention: 16 q-tiles(128) x 16 heads x 2 batches = 512 blocks,
    // 4 waves x 2 q-groups (shared K/V LDS reads)
    attn<<<512, 256, 0, stream>>>(Y, Vt, tab, Ob);

    // output projection: [4096,1024] @ [1024,1024]^T -> fp32 out, 64x128 tiles
    gemm_bt<0><<<dim3(8, 64), 256, 0, stream>>>(Ob, Wob, out, nullptr, 4096, 1024, 1024);
}

// Round 21
// 116.862 us; speedup vs baseline: 1.0558x; 1.0558x over previous
//
#include <hip/hip_runtime.h>

using half8  = __attribute__((ext_vector_type(8))) _Float16;
using half4  = __attribute__((ext_vector_type(4))) _Float16;
using half2v = __attribute__((ext_vector_type(2))) _Float16;
using fp16x2 = __attribute__((ext_vector_type(2))) __fp16;
using f32x4  = __attribute__((ext_vector_type(4))) float;

#define BB 2
#define SS 2048
#define DD 1024
#define HH 16
#define KVH 4
#define HDIM 64
#define NQK 1280    // Q(1024) | K(256) columns of QK projection
#define LOG2E 1.4426950408889634f

// async global->LDS, 16B per lane, linear LDS dest (wave-uniform base + lane*16)
#define GLDS(g, l) __builtin_amdgcn_global_load_lds( \
    (const __attribute__((address_space(1))) void*)(g), \
    (__attribute__((address_space(3))) void*)(l), 16, 0, 0)

__device__ __forceinline__ f32x4 mfma16(half4 a, half4 b, f32x4 c) {
    return __builtin_amdgcn_mfma_f32_16x16x16f16(a, b, c, 0, 0, 0);
}

__device__ __forceinline__ float fexp2(float x) {
#if __has_builtin(__builtin_amdgcn_exp2f)
    return __builtin_amdgcn_exp2f(x);
#else
    return exp2f(x);
#endif
}

__device__ __forceinline__ half2v cvt_pk_f16(float a, float b) {
    fp16x2 r = __builtin_amdgcn_cvt_pkrtz(a, b);
    return __builtin_bit_cast(half2v, r);
}

// Attn K/V LDS tile [64 rows][64 halves], row stride 128B, XOR-swizzled 16B
// slots: slot' = slot ^ (row & 7). Applied on BOTH ds_write and all reads.
__device__ __forceinline__ int kv_off(int row, int hcol) {
    return row * 64 + ((((hcol >> 3) ^ row) & 7) << 3) + (hcol & 7);
}

// GEMM LDS tile [rows][32 halves], row stride 64B, XOR-swizzled 16B slots:
// slot' = slot ^ (row & 3). Reader-side helper (writer swizzles GLDS source).
__device__ __forceinline__ int gm_off(int row, int slot) {
    return row * 32 + (((slot ^ row) & 3) << 3);
}

// T5 bucket via integer thresholds (matches numpy fp32 logf semantics at all
// integer rel positions; verified boundary cases 12/16/23/32/46/64/91).
__device__ __forceinline__ int rel_large(int rel) { // rel >= 8
    int n;
    if (rel < 12) n = 0; else if (rel < 16) n = 1; else if (rel < 23) n = 2;
    else if (rel < 32) n = 3; else if (rel < 46) n = 4; else if (rel < 64) n = 5;
    else if (rel < 91) n = 6; else if (rel < 128) n = 7; else n = 8;
    int large = 8 + n;
    return large > 15 ? 15 : large;
}

// ---------------------------------------------------------------------------
// Fused prep: blocks 0..2559 -> weights; 2560..6655 -> cast x; 6656..6911 ->
// bias table. Q-rows of Wqk and the bias table are PRE-SCALED by log2e so the
// attention softmax runs in exp2 domain.
// rows 1280..1535 use RAW pooled Wv (value_scale unused: reference bug).
__global__ void prep_all(const float* __restrict__ x,
                         const float* __restrict__ Wq, const float* __restrict__ Wk,
                         const float* __restrict__ Wv, const float* __restrict__ Wo,
                         const float* __restrict__ ksc, const float* __restrict__ bias_emb,
                         _Float16* __restrict__ Wqk, _Float16* __restrict__ Wvb,
                         _Float16* __restrict__ Wob, float* __restrict__ tab,
                         _Float16* __restrict__ Xh)
{
    int bid = blockIdx.x;
    if (bid < 2560) {
        int row = bid;
        int c = threadIdx.x * 4;
        if (row < NQK) {
            if (row < 1024) {
                #pragma unroll
                for (int j = 0; j < 4; ++j)
                    Wqk[(size_t)row * DD + c + j] = (_Float16)(Wq[(size_t)row * DD + c + j] * LOG2E);
            } else {
                int kh = row - 1024;                  // 0..255
                int kvi = kh >> 6, hd = kh & 63;
                #pragma unroll
                for (int j = 0; j < 4; ++j) {
                    float s = 0.f;
                    #pragma unroll
                    for (int g = 0; g < 4; ++g)
                        s += Wk[(size_t)((kvi * 4 + g) * 64 + hd) * DD + c + j] * ksc[kvi * 4 + g];
                    Wqk[(size_t)row * DD + c + j] = (_Float16)s;
                }
            }
        } else if (row < 1536) {
            int vh = row - 1280;
            int kvi = vh >> 6, hd = vh & 63;
            #pragma unroll
            for (int j = 0; j < 4; ++j) {
                float s = 0.f;
                #pragma unroll
                for (int g = 0; g < 4; ++g)
                    s += Wv[(size_t)((kvi * 4 + g) * 64 + hd) * DD + c + j];
                Wvb[(size_t)vh * DD + c + j] = (_Float16)s;
            }
        } else {
            int r = row - 1536;
            #pragma unroll
            for (int j = 0; j < 4; ++j)
                Wob[(size_t)r * DD + c + j] = (_Float16)Wo[(size_t)r * DD + c + j];
        }
    } else if (bid < 6656) {
        int idx = ((bid - 2560) * 256 + threadIdx.x) * 4;
        float4 v = *(const float4*)(x + idx);
        half4 o = { (_Float16)v.x, (_Float16)v.y, (_Float16)v.z, (_Float16)v.w };
        *(half4*)(Xh + idx) = o;
    } else {
        int idx = (bid - 6656) * 256 + threadIdx.x;
        if (idx < HH * 4095) {
            int h = idx / 4095;
            int dpos = idx % 4095;
            int d = dpos - 2047;
            int rel = d < 0 ? -d : d;
            int bucket = (rel < 8) ? rel : rel_large(rel);
            if (d > 0) bucket += 16;
            tab[(size_t)h * 4095 + dpos] = bias_emb[bucket * HH + h] * LOG2E;
        }
    }
}

// ---------------------------------------------------------------------------
// C = A[M,K] @ B[N,K]^T, fp16 in, fp32 accum. 64x128 tile (M-tile 64 for
// exact CU balance: gemm<3> 768 blk = 3/CU, gemm<0> 512 blk = 2/CU), BK=32,
// 4 waves (2Mx2N, each 32x64 = 2x4 frags), 2-phase double-buffered
// global_load_lds staging (pre-swizzled source col; reads via gm_off).
// OUTK 0: C0 fp32 row-major (ldc stride).
// OUTK 3: fused projection output: cols < 1280 -> C0 fp16 row-major (ldc);
//         cols >= 1280 -> C1 fp16 TRANSPOSED (C1[(col-1280)*M + row]).
template<int OUTK>
__global__ __launch_bounds__(256) void gemm_bt(const _Float16* __restrict__ A,
                                               const _Float16* __restrict__ B,
                                               void* __restrict__ C0,
                                               _Float16* __restrict__ C1,
                                               int M, int K, int ldc)
{
    __shared__ __align__(16) _Float16 As[2][64 * 32];
    __shared__ __align__(16) _Float16 Bs[2][128 * 32];

    // XCD-bijective remap of linear block id (grid size % 8 == 0)
    int nwg = gridDim.x * gridDim.y;
    int lid = blockIdx.y * gridDim.x + blockIdx.x;
    int sid = (lid & 7) * (nwg >> 3) + (lid >> 3);
    int m0 = (sid / gridDim.x) * 64, n0 = (sid % gridDim.x) * 128;

    int t = threadIdx.x;
    int wv = t >> 6, lane = t & 63;
    int wm = wv >> 1, wn = wv & 1;
    int lr = lane & 15, lg = lane >> 4;
    int srow = lane >> 2;            // 0..15 within chunk (row = chunk*16+srow)
    // GLDS pre-swizzled source column (lane's linear slot holds logical slot^row)
    int scol = (((lane & 3) ^ (srow & 3)) << 3);
    f32x4 acc[2][4] = {};

#define GSTAGE(BUF, K0)                                                       \
    {                                                                         \
        /* A: 4 chunks of 16 rows; wave wv stages chunk wv */                 \
        GLDS(A + (size_t)(m0 + wv * 16 + srow) * K + (K0) + scol,             \
             &As[BUF][wv * 512 + lane * 8]);                                  \
        _Pragma("unroll")                                                     \
        for (int i_ = 0; i_ < 2; ++i_) {                                      \
            int chunk_ = wv * 2 + i_;                                         \
            GLDS(B + (size_t)(n0 + chunk_ * 16 + srow) * K + (K0) + scol,     \
                 &Bs[BUF][chunk_ * 512 + lane * 8]);                          \
        }                                                                     \
    }

    GSTAGE(0, 0);
    __syncthreads();          // drains vmcnt -> buf0 ready
    int cur = 0;

    for (int k0 = 0; k0 < K; k0 += 32) {
        if (k0 + 32 < K) GSTAGE(cur ^ 1, k0 + 32);   // async prefetch
        half8 af[2], bfr[4];
        #pragma unroll
        for (int mi = 0; mi < 2; ++mi)
            af[mi] = *(const half8*)(&As[cur][gm_off(wm * 32 + mi * 16 + lr, lg)]);
        #pragma unroll
        for (int ni = 0; ni < 4; ++ni)
            bfr[ni] = *(const half8*)(&Bs[cur][gm_off(wn * 64 + ni * 16 + lr, lg)]);
        __builtin_amdgcn_s_setprio(1);
        #pragma unroll
        for (int mi = 0; mi < 2; ++mi)
            #pragma unroll
            for (int ni = 0; ni < 4; ++ni)
                acc[mi][ni] = __builtin_amdgcn_mfma_f32_16x16x32_f16(af[mi], bfr[ni], acc[mi][ni], 0, 0, 0);
        __builtin_amdgcn_s_setprio(0);
        __syncthreads();      // drains prefetch vmcnt; readers of cur done
        cur ^= 1;
    }
#undef GSTAGE

    #pragma unroll
    for (int mi = 0; mi < 2; ++mi) {
        #pragma unroll
        for (int ni = 0; ni < 4; ++ni) {
            int rowb = m0 + wm * 32 + mi * 16 + 4 * lg;
            int col  = n0 + wn * 64 + ni * 16 + lr;
            if constexpr (OUTK == 0) {
                #pragma unroll
                for (int r = 0; r < 4; ++r)
                    ((float*)C0)[(size_t)(rowb + r) * ldc + col] = acc[mi][ni][r];
            } else {
                if (n0 < 1280) {
                    #pragma unroll
                    for (int r = 0; r < 4; ++r)
                        ((_Float16*)C0)[(size_t)(rowb + r) * ldc + col] = (_Float16)acc[mi][ni][r];
                } else {
                    half4 o = { (_Float16)acc[mi][ni][0], (_Float16)acc[mi][ni][1],
                                (_Float16)acc[mi][ni][2], (_Float16)acc[mi][ni][3] };
                    *(half4*)(C1 + (size_t)(col - 1280) * M + rowb) = o;
                }
            }
        }
    }
}

// ---------------------------------------------------------------------------
// Flash attention, swapped-operand QK^T, fp16, 8 waves x 128 q-rows per block
// (one 64-key K/V staging serves 2x the Q rows of the 4-wave version).
// Double-buffered async staging, exp2-domain softmax, XOR-swizzled K/V LDS.
// Lane's q-row = w*16+lr (softmax partners at lane^16, lane^32).
// Far tiles (key0-q0 >= 256 or <= -192): saturated bucket -> uniform bias
// folded into the softmax offset.
// NOTE (R12-R20 post-mortems): this config is a robust local optimum (70.6us).
// Failed variants: min-waves bound (spills, 354MB scratch); wave key-split
// (fixed costs don't shrink); block key-split (occupancy stuck at 37%);
// K direct-from-L2 (strided 16B/lane reads -> latency-bound, 132us);
// 4-wave 2-q-group sharing (halved conflicts but occupancy 37->19%, 77us).
__global__ __launch_bounds__(512) void attn(const _Float16* __restrict__ Y,
                                            const _Float16* __restrict__ Vt,
                                            const float* __restrict__ tab,
                                            _Float16* __restrict__ O)
{
    // bijective XCD swizzle: 512 = 8 * 64; blocks sharing a (b,kv) K/V slab
    // (64 consecutive logical ids) land on one XCD's L2.
    int blk = (blockIdx.x & 7) * 64 + (blockIdx.x >> 3);
    int qb = blk & 15, h = (blk >> 4) & 15, b = blk >> 8;
    int kv = h >> 2;
    int q0 = qb * 128;
    int t = threadIdx.x, w = t >> 6, lane = t & 63, lr = lane & 15, lg = lane >> 4;

    __shared__ __align__(16) _Float16 Ks[2][64 * 64];
    __shared__ __align__(16) _Float16 Vst[2][64 * 64];
    __shared__ float bias_s[2][192];

    const size_t yoff = (size_t)(b * SS + q0 + w * 16 + lr) * NQK + h * 64;
    half8 aq0 = *(const half8*)(Y + yoff + lg * 8);
    half8 aq1 = *(const half8*)(Y + yoff + 32 + lg * 8);

    // far-tile uniform bias values (bucket saturated at |d|>=128), log2-scaled
    const float bias_neg = tab[(size_t)h * 4095 + 0];      // key << q
    const float bias_pos = tab[(size_t)h * 4095 + 4094];   // key >> q

    f32x4 acc_o[4] = {};
    float m = -1e30f, l = 0.f;
    const int bb = 127 - w * 16 - lr + 4 * lg;   // bias base: + dt*16 + r

    // staging registers (one K row-chunk + one V row-chunk per thread)
    uint4 kreg, vreg;
    float breg = 0.f;
    const int srow = t >> 3, sc8 = (t & 7) << 3;   // 512 threads cover 64 rows x 64 halves

#define FAR(K0) (((K0) >= q0 + 256) || ((K0) <= q0 - 192))

#define ATTN_LOAD(KEY0)                                                          \
    {                                                                            \
        int k0_ = (KEY0);                                                        \
        kreg = *(const uint4*)(Y + (size_t)(b * SS + k0_ + srow) * NQK + 1024 + kv * 64 + sc8); \
        vreg = *(const uint4*)(Vt + (size_t)(kv * 64 + srow) * 4096 + b * SS + k0_ + sc8); \
        if (!FAR(k0_) && t < 192) {                                              \
            int ti = k0_ - q0 + t + 1920;                                        \
            ti = ti < 0 ? 0 : (ti > 4094 ? 4094 : ti);                           \
            breg = tab[(size_t)h * 4095 + ti];                                   \
        }                                                                        \
    }

#define ATTN_WRITE(BUF, KEY0)                                                    \
    {                                                                            \
        int bf_ = (BUF);                                                         \
        *(uint4*)(&Ks[bf_][kv_off(srow, sc8)]) = kreg;                           \
        *(uint4*)(&Vst[bf_][kv_off(srow, sc8)]) = vreg;                          \
        if (!FAR(KEY0) && t < 192) bias_s[bf_][t] = breg;                        \
    }

    ATTN_LOAD(0);
    ATTN_WRITE(0, 0);
    __syncthreads();
    int cur = 0;

    for (int key0 = 0; key0 < SS; key0 += 64) {
        if (key0 + 64 < SS) ATTN_LOAD(key0 + 64);   // async: regs used only in WRITE

        const _Float16* ks = Ks[cur];
        const _Float16* vs = Vst[cur];
        bool far = FAR(key0);

        // swapped QK^T: sc[dt][r] = S2[key=key0+dt*16+4lg+r][q=w*16+lr] (log2)
        f32x4 z = {0.f, 0.f, 0.f, 0.f};
        f32x4 sc[4];
        __builtin_amdgcn_s_setprio(1);
        #pragma unroll
        for (int dt = 0; dt < 4; ++dt) {
            half8 bk0 = *(const half8*)(&ks[kv_off(dt * 16 + lr, lg * 8)]);
            half8 bk1 = *(const half8*)(&ks[kv_off(dt * 16 + lr, 32 + lg * 8)]);
            sc[dt] = __builtin_amdgcn_mfma_f32_16x16x32_f16(bk0, aq0, z, 0, 0, 0);
            sc[dt] = __builtin_amdgcn_mfma_f32_16x16x32_f16(bk1, aq1, sc[dt], 0, 0, 0);
        }
        __builtin_amdgcn_s_setprio(0);

        float c;
        if (!far) {
            #pragma unroll
            for (int dt = 0; dt < 4; ++dt)
                #pragma unroll
                for (int r = 0; r < 4; ++r)
                    sc[dt][r] += bias_s[cur][bb + dt * 16 + r];
            c = 0.f;
        } else {
            c = (key0 > q0) ? bias_pos : bias_neg;
        }

        // per-lane online softmax with deferred rescale (THR=8 log2-units)
        float pmax = sc[0][0];
        #pragma unroll
        for (int dt = 0; dt < 4; ++dt)
            #pragma unroll
            for (int r = 0; r < 4; ++r) pmax = fmaxf(pmax, sc[dt][r]);
        pmax = fmaxf(pmax, __shfl_xor(pmax, 16, 64));
        pmax = fmaxf(pmax, __shfl_xor(pmax, 32, 64));
        pmax += c;                                    // effective max incl. bias
        if (__any(pmax > m + 8.f)) {
            float mn = fmaxf(m, pmax);
            float scale = fexp2(m - mn);
            l *= scale;
            #pragma unroll
            for (int odt = 0; odt < 4; ++odt)
                #pragma unroll
                for (int r = 0; r < 4; ++r) acc_o[odt][r] *= scale;
            m = mn;
        }
        float moff = m - c;                           // P = 2^(sc + c - m)
        float rs = 0.f;
        #pragma unroll
        for (int dt = 0; dt < 4; ++dt)
            #pragma unroll
            for (int r = 0; r < 4; ++r) {
                float p = fexp2(sc[dt][r] - moff);
                sc[dt][r] = p;
                rs += p;
            }
        rs += __shfl_xor(rs, 16, 64);
        rs += __shfl_xor(rs, 32, 64);
        l += rs;

        // pack P to fp16 B-fragments (k=4*lg+e matches 16x16x16 B layout)
        half4 pf[4];
        #pragma unroll
        for (int dt = 0; dt < 4; ++dt) {
            half2v p01 = cvt_pk_f16(sc[dt][0], sc[dt][1]);
            half2v p23 = cvt_pk_f16(sc[dt][2], sc[dt][3]);
            pf[dt] = { p01[0], p01[1], p23[0], p23[1] };
        }

        // PV: acc_o[odt] (= O^T[d=odt*16+4lg+r][q]) += V^T frag x P frag
        __builtin_amdgcn_s_setprio(1);
        #pragma unroll
        for (int odt = 0; odt < 4; ++odt)
            #pragma unroll
            for (int dt = 0; dt < 4; ++dt) {
                half4 vf = *(const half4*)(&vs[kv_off(odt * 16 + lr, dt * 16 + 4 * lg)]);
                acc_o[odt] = mfma16(vf, pf[dt], acc_o[odt]);
            }
        __builtin_amdgcn_s_setprio(0);

        if (key0 + 64 < SS) {
            ATTN_WRITE(cur ^ 1, key0 + 64);   // waits vmcnt for regs, fills other buf
            __syncthreads();                  // single barrier per tile
            cur ^= 1;
        }
    }

    // epilogue: lane writes its q-row, d = odt*16 + 4*lg + r (half4 stores)
    float inv = 1.f / l;
    _Float16* orow = O + (size_t)(b * SS + q0 + w * 16 + lr) * 1024 + h * 64;
    #pragma unroll
    for (int odt = 0; odt < 4; ++odt) {
        half4 o = { (_Float16)(acc_o[odt][0] * inv), (_Float16)(acc_o[odt][1] * inv),
                    (_Float16)(acc_o[odt][2] * inv), (_Float16)(acc_o[odt][3] * inv) };
        *(half4*)(orow + odt * 16 + 4 * lg) = o;
    }
#undef ATTN_LOAD
#undef ATTN_WRITE
#undef FAR
}

// ---------------------------------------------------------------------------
extern "C" void kernel_launch(void* const* d_in, const int* in_sizes, int n_in,
                              void* d_out, int out_size, void* d_ws, size_t ws_size,
                              hipStream_t stream)
{
    const float* x   = (const float*)d_in[0];
    const float* Wq  = (const float*)d_in[1];
    const float* Wk  = (const float*)d_in[2];
    const float* Wv  = (const float*)d_in[3];
    const float* Wo  = (const float*)d_in[4];
    const float* ksc = (const float*)d_in[5];
    // d_in[6] (value_scale) intentionally unused — reference pools raw Wv
    const float* bias_emb = (const float*)d_in[7];
    float* out = (float*)d_out;

    char* ws = (char*)d_ws;
    // workspace layout (bytes); Wqk and Wvb MUST be adjacent (fused GEMM B)
    _Float16* Wqk = (_Float16*)(ws);                  // 1280*1024*2 =  2,621,440
    _Float16* Wvb = (_Float16*)(ws + 2621440);        //  256*1024*2 =    524,288
    _Float16* Wob = (_Float16*)(ws + 3145728);        // 1024*1024*2 =  2,097,152
    float*    tab = (float*)(ws + 5242880);           // 16*4095*4   =    262,080 (+pad)
    _Float16* Xh  = (_Float16*)(ws + 5505024);        // 4096*1024*2 =  8,388,608
    _Float16* Y   = (_Float16*)(ws + 13893632);       // 4096*1280*2 = 10,485,760
    _Float16* Vt  = (_Float16*)(ws + 24379392);       //  256*4096*2 =  2,097,152
    _Float16* Ob  = (_Float16*)(ws + 26476544);       // 4096*1024*2 =  8,388,608
    // total: 34,865,152 bytes

    // fused prep: weights (log2e-folded Q), x cast, bias table (log2e-scaled)
    prep_all<<<6912, 256, 0, stream>>>(x, Wq, Wk, Wv, Wo, ksc, bias_emb,
                                       Wqk, Wvb, Wob, tab, Xh);

    // fused Q|K|V projection: [4096,1024] @ [1536,1024]^T, 64x128 tiles
    // cols 0..1279 -> Y row-major; cols 1280..1535 -> Vt transposed
    gemm_bt<3><<<dim3(12, 64), 256, 0, stream>>>(Xh, Wqk, Y, Vt, 4096, 1024, NQK);

    // flash attention: 16 q-tiles(128) x 16 heads x 2 batches = 512 blocks,
    // 8 waves x 128 q-rows
    attn<<<512, 512, 0, stream>>>(Y, Vt, tab, Ob);

    // output projection: [4096,1024] @ [1024,1024]^T -> fp32 out, 64x128 tiles
    gemm_bt<0><<<dim3(8, 64), 256, 0, stream>>>(Ob, Wob, out, nullptr, 4096, 1024, 1024);
}

// Round 22
// 116.358 us; speedup vs baseline: 1.0604x; 1.0043x over previous
//
#include <hip/hip_runtime.h>

using half8  = __attribute__((ext_vector_type(8))) _Float16;
using half4  = __attribute__((ext_vector_type(4))) _Float16;
using half2v = __attribute__((ext_vector_type(2))) _Float16;
using fp16x2 = __attribute__((ext_vector_type(2))) __fp16;
using f32x4  = __attribute__((ext_vector_type(4))) float;

#define BB 2
#define SS 2048
#define DD 1024
#define HH 16
#define KVH 4
#define HDIM 64
#define NQK 1280    // Q(1024) | K(256) columns of QK projection
#define LOG2E 1.4426950408889634f

// async global->LDS, 16B per lane, linear LDS dest (wave-uniform base + lane*16)
#define GLDS(g, l) __builtin_amdgcn_global_load_lds( \
    (const __attribute__((address_space(1))) void*)(g), \
    (__attribute__((address_space(3))) void*)(l), 16, 0, 0)

__device__ __forceinline__ f32x4 mfma16(half4 a, half4 b, f32x4 c) {
    return __builtin_amdgcn_mfma_f32_16x16x16f16(a, b, c, 0, 0, 0);
}

__device__ __forceinline__ float fexp2(float x) {
#if __has_builtin(__builtin_amdgcn_exp2f)
    return __builtin_amdgcn_exp2f(x);
#else
    return exp2f(x);
#endif
}

__device__ __forceinline__ half2v cvt_pk_f16(float a, float b) {
    fp16x2 r = __builtin_amdgcn_cvt_pkrtz(a, b);
    return __builtin_bit_cast(half2v, r);
}

// Attn K/V LDS tile [64 rows][64 halves], row stride 128B, XOR-swizzled 16B
// slots: slot' = slot ^ (row & 7). Applied on BOTH ds_write and all reads.
__device__ __forceinline__ int kv_off(int row, int hcol) {
    return row * 64 + ((((hcol >> 3) ^ row) & 7) << 3) + (hcol & 7);
}

// GEMM LDS tile [rows][32 halves], row stride 64B, XOR-swizzled 16B slots:
// slot' = slot ^ (row & 3). Reader-side helper (writer swizzles GLDS source).
__device__ __forceinline__ int gm_off(int row, int slot) {
    return row * 32 + (((slot ^ row) & 3) << 3);
}

// T5 bucket via integer thresholds (matches numpy fp32 logf semantics at all
// integer rel positions; verified boundary cases 12/16/23/32/46/64/91).
__device__ __forceinline__ int rel_large(int rel) { // rel >= 8
    int n;
    if (rel < 12) n = 0; else if (rel < 16) n = 1; else if (rel < 23) n = 2;
    else if (rel < 32) n = 3; else if (rel < 46) n = 4; else if (rel < 64) n = 5;
    else if (rel < 91) n = 6; else if (rel < 128) n = 7; else n = 8;
    int large = 8 + n;
    return large > 15 ? 15 : large;
}

// ---------------------------------------------------------------------------
// Fused prep: blocks 0..2559 -> weights; 2560..6655 -> cast x; 6656..6911 ->
// bias table. Q-rows of Wqk and the bias table are PRE-SCALED by log2e so the
// attention softmax runs in exp2 domain.
// rows 1280..1535 use RAW pooled Wv (value_scale unused: reference bug).
__global__ void prep_all(const float* __restrict__ x,
                         const float* __restrict__ Wq, const float* __restrict__ Wk,
                         const float* __restrict__ Wv, const float* __restrict__ Wo,
                         const float* __restrict__ ksc, const float* __restrict__ bias_emb,
                         _Float16* __restrict__ Wqk, _Float16* __restrict__ Wvb,
                         _Float16* __restrict__ Wob, float* __restrict__ tab,
                         _Float16* __restrict__ Xh)
{
    int bid = blockIdx.x;
    if (bid < 2560) {
        int row = bid;
        int c = threadIdx.x * 4;
        if (row < NQK) {
            if (row < 1024) {
                #pragma unroll
                for (int j = 0; j < 4; ++j)
                    Wqk[(size_t)row * DD + c + j] = (_Float16)(Wq[(size_t)row * DD + c + j] * LOG2E);
            } else {
                int kh = row - 1024;                  // 0..255
                int kvi = kh >> 6, hd = kh & 63;
                #pragma unroll
                for (int j = 0; j < 4; ++j) {
                    float s = 0.f;
                    #pragma unroll
                    for (int g = 0; g < 4; ++g)
                        s += Wk[(size_t)((kvi * 4 + g) * 64 + hd) * DD + c + j] * ksc[kvi * 4 + g];
                    Wqk[(size_t)row * DD + c + j] = (_Float16)s;
                }
            }
        } else if (row < 1536) {
            int vh = row - 1280;
            int kvi = vh >> 6, hd = vh & 63;
            #pragma unroll
            for (int j = 0; j < 4; ++j) {
                float s = 0.f;
                #pragma unroll
                for (int g = 0; g < 4; ++g)
                    s += Wv[(size_t)((kvi * 4 + g) * 64 + hd) * DD + c + j];
                Wvb[(size_t)vh * DD + c + j] = (_Float16)s;
            }
        } else {
            int r = row - 1536;
            #pragma unroll
            for (int j = 0; j < 4; ++j)
                Wob[(size_t)r * DD + c + j] = (_Float16)Wo[(size_t)r * DD + c + j];
        }
    } else if (bid < 6656) {
        int idx = ((bid - 2560) * 256 + threadIdx.x) * 4;
        float4 v = *(const float4*)(x + idx);
        half4 o = { (_Float16)v.x, (_Float16)v.y, (_Float16)v.z, (_Float16)v.w };
        *(half4*)(Xh + idx) = o;
    } else {
        int idx = (bid - 6656) * 256 + threadIdx.x;
        if (idx < HH * 4095) {
            int h = idx / 4095;
            int dpos = idx % 4095;
            int d = dpos - 2047;
            int rel = d < 0 ? -d : d;
            int bucket = (rel < 8) ? rel : rel_large(rel);
            if (d > 0) bucket += 16;
            tab[(size_t)h * 4095 + dpos] = bias_emb[bucket * HH + h] * LOG2E;
        }
    }
}

// ---------------------------------------------------------------------------
// C = A[M,K] @ B[N,K]^T, fp16 in, fp32 accum. 64x128 tile (M-tile 64 for
// exact CU balance: gemm<3> 768 blk = 3/CU, gemm<0> 512 blk = 2/CU), BK=32,
// 4 waves (2Mx2N, each 32x64 = 2x4 frags), 2-phase double-buffered
// global_load_lds staging (pre-swizzled source col; reads via gm_off).
// OUTK 0: C0 fp32 row-major (ldc stride).
// OUTK 3: fused projection output: cols < 1280 -> C0 fp16 row-major (ldc);
//         cols >= 1280 -> C1 fp16 TRANSPOSED (C1[(col-1280)*M + row]).
template<int OUTK>
__global__ __launch_bounds__(256) void gemm_bt(const _Float16* __restrict__ A,
                                               const _Float16* __restrict__ B,
                                               void* __restrict__ C0,
                                               _Float16* __restrict__ C1,
                                               int M, int K, int ldc)
{
    __shared__ __align__(16) _Float16 As[2][64 * 32];
    __shared__ __align__(16) _Float16 Bs[2][128 * 32];

    // XCD-bijective remap of linear block id (grid size % 8 == 0)
    int nwg = gridDim.x * gridDim.y;
    int lid = blockIdx.y * gridDim.x + blockIdx.x;
    int sid = (lid & 7) * (nwg >> 3) + (lid >> 3);
    int m0 = (sid / gridDim.x) * 64, n0 = (sid % gridDim.x) * 128;

    int t = threadIdx.x;
    int wv = t >> 6, lane = t & 63;
    int wm = wv >> 1, wn = wv & 1;
    int lr = lane & 15, lg = lane >> 4;
    int srow = lane >> 2;            // 0..15 within chunk (row = chunk*16+srow)
    // GLDS pre-swizzled source column (lane's linear slot holds logical slot^row)
    int scol = (((lane & 3) ^ (srow & 3)) << 3);
    f32x4 acc[2][4] = {};

#define GSTAGE(BUF, K0)                                                       \
    {                                                                         \
        /* A: 4 chunks of 16 rows; wave wv stages chunk wv */                 \
        GLDS(A + (size_t)(m0 + wv * 16 + srow) * K + (K0) + scol,             \
             &As[BUF][wv * 512 + lane * 8]);                                  \
        _Pragma("unroll")                                                     \
        for (int i_ = 0; i_ < 2; ++i_) {                                      \
            int chunk_ = wv * 2 + i_;                                         \
            GLDS(B + (size_t)(n0 + chunk_ * 16 + srow) * K + (K0) + scol,     \
                 &Bs[BUF][chunk_ * 512 + lane * 8]);                          \
        }                                                                     \
    }

    GSTAGE(0, 0);
    __syncthreads();          // drains vmcnt -> buf0 ready
    int cur = 0;

    for (int k0 = 0; k0 < K; k0 += 32) {
        if (k0 + 32 < K) GSTAGE(cur ^ 1, k0 + 32);   // async prefetch
        half8 af[2], bfr[4];
        #pragma unroll
        for (int mi = 0; mi < 2; ++mi)
            af[mi] = *(const half8*)(&As[cur][gm_off(wm * 32 + mi * 16 + lr, lg)]);
        #pragma unroll
        for (int ni = 0; ni < 4; ++ni)
            bfr[ni] = *(const half8*)(&Bs[cur][gm_off(wn * 64 + ni * 16 + lr, lg)]);
        __builtin_amdgcn_s_setprio(1);
        #pragma unroll
        for (int mi = 0; mi < 2; ++mi)
            #pragma unroll
            for (int ni = 0; ni < 4; ++ni)
                acc[mi][ni] = __builtin_amdgcn_mfma_f32_16x16x32_f16(af[mi], bfr[ni], acc[mi][ni], 0, 0, 0);
        __builtin_amdgcn_s_setprio(0);
        __syncthreads();      // drains prefetch vmcnt; readers of cur done
        cur ^= 1;
    }
#undef GSTAGE

    #pragma unroll
    for (int mi = 0; mi < 2; ++mi) {
        #pragma unroll
        for (int ni = 0; ni < 4; ++ni) {
            int rowb = m0 + wm * 32 + mi * 16 + 4 * lg;
            int col  = n0 + wn * 64 + ni * 16 + lr;
            if constexpr (OUTK == 0) {
                #pragma unroll
                for (int r = 0; r < 4; ++r)
                    ((float*)C0)[(size_t)(rowb + r) * ldc + col] = acc[mi][ni][r];
            } else {
                if (n0 < 1280) {
                    #pragma unroll
                    for (int r = 0; r < 4; ++r)
                        ((_Float16*)C0)[(size_t)(rowb + r) * ldc + col] = (_Float16)acc[mi][ni][r];
                } else {
                    half4 o = { (_Float16)acc[mi][ni][0], (_Float16)acc[mi][ni][1],
                                (_Float16)acc[mi][ni][2], (_Float16)acc[mi][ni][3] };
                    *(half4*)(C1 + (size_t)(col - 1280) * M + rowb) = o;
                }
            }
        }
    }
}

// ---------------------------------------------------------------------------
// Flash attention, swapped-operand QK^T, fp16, 8 waves x 128 q-rows per block,
// QUAD-BUFFERED LDS: 4 K/V buffers, tiles processed in pairs with ONE
// __syncthreads per 128 keys (vs per 64) — halves the per-tile sync drain
// where all 8 waves convene. Writes always target the alternate buffer pair;
// the barrier separates iter-i reads-of-cur from iter-(i+1) writes-to-cur.
// exp2-domain softmax, XOR-swizzled K/V LDS, far-tile uniform bias.
// NOTE (R12-R20 post-mortems): per-tile structure is a robust local optimum.
// Failed variants: min-waves bound (spills); wave key-split; block key-split;
// K direct-from-L2 (strided reads); 4-wave q-group sharing (occupancy loss).
__global__ __launch_bounds__(512) void attn(const _Float16* __restrict__ Y,
                                            const _Float16* __restrict__ Vt,
                                            const float* __restrict__ tab,
                                            _Float16* __restrict__ O)
{
    // bijective XCD swizzle: 512 = 8 * 64; blocks sharing a (b,kv) K/V slab
    // (64 consecutive logical ids) land on one XCD's L2.
    int blk = (blockIdx.x & 7) * 64 + (blockIdx.x >> 3);
    int qb = blk & 15, h = (blk >> 4) & 15, b = blk >> 8;
    int kv = h >> 2;
    int q0 = qb * 128;
    int t = threadIdx.x, w = t >> 6, lane = t & 63, lr = lane & 15, lg = lane >> 4;

    __shared__ __align__(16) _Float16 Ks[4][64 * 64];
    __shared__ __align__(16) _Float16 Vst[4][64 * 64];
    __shared__ float bias_s[4][192];

    const size_t yoff = (size_t)(b * SS + q0 + w * 16 + lr) * NQK + h * 64;
    half8 aq0 = *(const half8*)(Y + yoff + lg * 8);
    half8 aq1 = *(const half8*)(Y + yoff + 32 + lg * 8);

    // far-tile uniform bias values (bucket saturated at |d|>=128), log2-scaled
    const float bias_neg = tab[(size_t)h * 4095 + 0];      // key << q
    const float bias_pos = tab[(size_t)h * 4095 + 4094];   // key >> q

    f32x4 acc_o[4] = {};
    float m = -1e30f, l = 0.f;
    const int bb = 127 - w * 16 - lr + 4 * lg;   // bias base: + dt*16 + r

    // two independent staging register sets (A/B tiles of a pair)
    uint4 kregA, vregA, kregB, vregB;
    float bregA = 0.f, bregB = 0.f;
    const int srow = t >> 3, sc8 = (t & 7) << 3;   // 512 threads cover 64 rows x 64 halves

#define FAR(K0) (((K0) >= q0 + 256) || ((K0) <= q0 - 192))

    auto LOAD = [&](int k0_, uint4& kreg, uint4& vreg, float& breg) {
        kreg = *(const uint4*)(Y + (size_t)(b * SS + k0_ + srow) * NQK + 1024 + kv * 64 + sc8);
        vreg = *(const uint4*)(Vt + (size_t)(kv * 64 + srow) * 4096 + b * SS + k0_ + sc8);
        if (!FAR(k0_) && t < 192) {
            int ti = k0_ - q0 + t + 1920;
            ti = ti < 0 ? 0 : (ti > 4094 ? 4094 : ti);
            breg = tab[(size_t)h * 4095 + ti];
        }
    };
    auto WRITE = [&](int buf, int k0_, const uint4& kreg, const uint4& vreg, float breg) {
        *(uint4*)(&Ks[buf][kv_off(srow, sc8)]) = kreg;
        *(uint4*)(&Vst[buf][kv_off(srow, sc8)]) = vreg;
        if (!FAR(k0_) && t < 192) bias_s[buf][t] = breg;
    };
    auto COMPUTE = [&](int key0, int buf) {
        const _Float16* ks = Ks[buf];
        const _Float16* vs = Vst[buf];
        bool far = FAR(key0);

        // swapped QK^T: sc[dt][r] = S2[key=key0+dt*16+4lg+r][q=w*16+lr] (log2)
        f32x4 z = {0.f, 0.f, 0.f, 0.f};
        f32x4 sc[4];
        __builtin_amdgcn_s_setprio(1);
        #pragma unroll
        for (int dt = 0; dt < 4; ++dt) {
            half8 bk0 = *(const half8*)(&ks[kv_off(dt * 16 + lr, lg * 8)]);
            half8 bk1 = *(const half8*)(&ks[kv_off(dt * 16 + lr, 32 + lg * 8)]);
            sc[dt] = __builtin_amdgcn_mfma_f32_16x16x32_f16(bk0, aq0, z, 0, 0, 0);
            sc[dt] = __builtin_amdgcn_mfma_f32_16x16x32_f16(bk1, aq1, sc[dt], 0, 0, 0);
        }
        __builtin_amdgcn_s_setprio(0);

        float c;
        if (!far) {
            #pragma unroll
            for (int dt = 0; dt < 4; ++dt)
                #pragma unroll
                for (int r = 0; r < 4; ++r)
                    sc[dt][r] += bias_s[buf][bb + dt * 16 + r];
            c = 0.f;
        } else {
            c = (key0 > q0) ? bias_pos : bias_neg;
        }

        // per-lane online softmax with deferred rescale (THR=8 log2-units)
        float pmax = sc[0][0];
        #pragma unroll
        for (int dt = 0; dt < 4; ++dt)
            #pragma unroll
            for (int r = 0; r < 4; ++r) pmax = fmaxf(pmax, sc[dt][r]);
        pmax = fmaxf(pmax, __shfl_xor(pmax, 16, 64));
        pmax = fmaxf(pmax, __shfl_xor(pmax, 32, 64));
        pmax += c;                                    // effective max incl. bias
        if (__any(pmax > m + 8.f)) {
            float mn = fmaxf(m, pmax);
            float scale = fexp2(m - mn);
            l *= scale;
            #pragma unroll
            for (int odt = 0; odt < 4; ++odt)
                #pragma unroll
                for (int r = 0; r < 4; ++r) acc_o[odt][r] *= scale;
            m = mn;
        }
        float moff = m - c;                           // P = 2^(sc + c - m)
        float rs = 0.f;
        #pragma unroll
        for (int dt = 0; dt < 4; ++dt)
            #pragma unroll
            for (int r = 0; r < 4; ++r) {
                float p = fexp2(sc[dt][r] - moff);
                sc[dt][r] = p;
                rs += p;
            }
        rs += __shfl_xor(rs, 16, 64);
        rs += __shfl_xor(rs, 32, 64);
        l += rs;

        // pack P to fp16 B-fragments (k=4*lg+e matches 16x16x16 B layout)
        half4 pf[4];
        #pragma unroll
        for (int dt = 0; dt < 4; ++dt) {
            half2v p01 = cvt_pk_f16(sc[dt][0], sc[dt][1]);
            half2v p23 = cvt_pk_f16(sc[dt][2], sc[dt][3]);
            pf[dt] = { p01[0], p01[1], p23[0], p23[1] };
        }

        // PV: acc_o[odt] (= O^T[d=odt*16+4lg+r][q]) += V^T frag x P frag
        __builtin_amdgcn_s_setprio(1);
        #pragma unroll
        for (int odt = 0; odt < 4; ++odt)
            #pragma unroll
            for (int dt = 0; dt < 4; ++dt) {
                half4 vf = *(const half4*)(&vs[kv_off(odt * 16 + lr, dt * 16 + 4 * lg)]);
                acc_o[odt] = mfma16(vf, pf[dt], acc_o[odt]);
            }
        __builtin_amdgcn_s_setprio(0);
    };

    // prologue: fill buffer pair 0 (bufs 0,1)
    LOAD(0, kregA, vregA, bregA);
    LOAD(64, kregB, vregB, bregB);
    WRITE(0, 0, kregA, vregA, bregA);
    WRITE(1, 64, kregB, vregB, bregB);
    __syncthreads();
    int p = 0;

    for (int key0 = 0; key0 < SS; key0 += 128) {
        bool more = (key0 + 128) < SS;
        if (more) {
            LOAD(key0 + 128, kregA, vregA, bregA);   // both prefetches in flight
            LOAD(key0 + 192, kregB, vregB, bregB);
        }
        COMPUTE(key0, p * 2);
        if (more) WRITE((p ^ 1) * 2, key0 + 128, kregA, vregA, bregA);
        COMPUTE(key0 + 64, p * 2 + 1);
        if (more) {
            WRITE((p ^ 1) * 2 + 1, key0 + 192, kregB, vregB, bregB);
            __syncthreads();                          // ONE barrier per 128 keys
            p ^= 1;
        }
    }

    // epilogue: lane writes its q-row, d = odt*16 + 4*lg + r (half4 stores)
    float inv = 1.f / l;
    _Float16* orow = O + (size_t)(b * SS + q0 + w * 16 + lr) * 1024 + h * 64;
    #pragma unroll
    for (int odt = 0; odt < 4; ++odt) {
        half4 o = { (_Float16)(acc_o[odt][0] * inv), (_Float16)(acc_o[odt][1] * inv),
                    (_Float16)(acc_o[odt][2] * inv), (_Float16)(acc_o[odt][3] * inv) };
        *(half4*)(orow + odt * 16 + 4 * lg) = o;
    }
#undef FAR
}

// ---------------------------------------------------------------------------
extern "C" void kernel_launch(void* const* d_in, const int* in_sizes, int n_in,
                              void* d_out, int out_size, void* d_ws, size_t ws_size,
                              hipStream_t stream)
{
    const float* x   = (const float*)d_in[0];
    const float* Wq  = (const float*)d_in[1];
    const float* Wk  = (const float*)d_in[2];
    const float* Wv  = (const float*)d_in[3];
    const float* Wo  = (const float*)d_in[4];
    const float* ksc = (const float*)d_in[5];
    // d_in[6] (value_scale) intentionally unused — reference pools raw Wv
    const float* bias_emb = (const float*)d_in[7];
    float* out = (float*)d_out;

    char* ws = (char*)d_ws;
    // workspace layout (bytes); Wqk and Wvb MUST be adjacent (fused GEMM B)
    _Float16* Wqk = (_Float16*)(ws);                  // 1280*1024*2 =  2,621,440
    _Float16* Wvb = (_Float16*)(ws + 2621440);        //  256*1024*2 =    524,288
    _Float16* Wob = (_Float16*)(ws + 3145728);        // 1024*1024*2 =  2,097,152
    float*    tab = (float*)(ws + 5242880);           // 16*4095*4   =    262,080 (+pad)
    _Float16* Xh  = (_Float16*)(ws + 5505024);        // 4096*1024*2 =  8,388,608
    _Float16* Y   = (_Float16*)(ws + 13893632);       // 4096*1280*2 = 10,485,760
    _Float16* Vt  = (_Float16*)(ws + 24379392);       //  256*4096*2 =  2,097,152
    _Float16* Ob  = (_Float16*)(ws + 26476544);       // 4096*1024*2 =  8,388,608
    // total: 34,865,152 bytes

    // fused prep: weights (log2e-folded Q), x cast, bias table (log2e-scaled)
    prep_all<<<6912, 256, 0, stream>>>(x, Wq, Wk, Wv, Wo, ksc, bias_emb,
                                       Wqk, Wvb, Wob, tab, Xh);

    // fused Q|K|V projection: [4096,1024] @ [1536,1024]^T, 64x128 tiles
    // cols 0..1279 -> Y row-major; cols 1280..1535 -> Vt transposed
    gemm_bt<3><<<dim3(12, 64), 256, 0, stream>>>(Xh, Wqk, Y, Vt, 4096, 1024, NQK);

    // flash attention: 16 q-tiles(128) x 16 heads x 2 batches = 512 blocks,
    // 8 waves x 128 q-rows, quad-buffered (1 barrier / 128 keys)
    attn<<<512, 512, 0, stream>>>(Y, Vt, tab, Ob);

    // output projection: [4096,1024] @ [1024,1024]^T -> fp32 out, 64x128 tiles
    gemm_bt<0><<<dim3(8, 64), 256, 0, stream>>>(Ob, Wob, out, nullptr, 4096, 1024, 1024);
}